// Round 4
// baseline (342.396 us; speedup 1.0000x reference)
//
#include <hip/hip_runtime.h>
#include <hip/hip_bf16.h>
#include <stdint.h>

typedef __attribute__((ext_vector_type(8))) short bf16x8;
typedef __attribute__((ext_vector_type(4))) float f32x4;
typedef unsigned short u16;
typedef unsigned int u32;

#define GLL(gp, lp) __builtin_amdgcn_global_load_lds( \
    (const __attribute__((address_space(1))) void*)(gp), \
    (__attribute__((address_space(3))) void*)(lp), 16, 0, 0)

__device__ __forceinline__ u16 f2bf_rne(float v) {
    u32 u = __float_as_uint(v);
    u32 r = (u + 0x7fffu + ((u >> 16) & 1u)) >> 16;
    return (u16)r;
}

// ---------------- pack kernels ----------------

// x (2048,39,16) f32  ->  xbd [32768][40] bf16, m = b*16+d, col 39 zero-pad
__global__ void pack_x_kernel(const float* __restrict__ x, u16* __restrict__ xbd) {
    int idx = blockIdx.x * 256 + threadIdx.x;
    if (idx >= 32768 * 40) return;
    int m = idx / 40, f = idx - m * 40;
    int b = m >> 4, d = m & 15;
    float v = (f < 39) ? x[(b * 39 + f) * 16 + d] : 0.0f;
    xbd[idx] = f2bf_rne(v);
}

// W0 (200,39,39) f32 -> Wp [224][1792] bf16, k = f*40+g, zero-padded
__global__ void pack_w0_kernel(const float* __restrict__ W, u16* __restrict__ Wp) {
    int idx = blockIdx.x * 256 + threadIdx.x;
    if (idx >= 224 * 1792) return;
    int o = idx / 1792, k = idx - o * 1792;
    int f = k / 40, g = k - f * 40;
    float v = (o < 200 && f < 39 && g < 39) ? W[(o * 39 + f) * 39 + g] : 0.0f;
    Wp[idx] = f2bf_rne(v);
}

// W1/W2 (200,39,200) f32 -> Wp [224][8192] bf16, k = f*208+g, zero-padded
__global__ void pack_w12_kernel(const float* __restrict__ W, u16* __restrict__ Wp) {
    int idx = blockIdx.x * 256 + threadIdx.x;
    if (idx >= 224 * 8192) return;
    int o = idx / 8192, k = idx - o * 8192;
    int f = k / 208, g = k - f * 208;
    float v = (o < 200 && f < 39 && g < 200) ? W[o * 7800 + f * 200 + g] : 0.0f;
    Wp[idx] = f2bf_rne(v);
}

// ---------------- main GEMM kernel ----------------
// C[m,o] = sum_k A[m,k]*Wp[o,k],  A[m, f*GS+g] = xbd[m,f]*h[m,g]
// grid 256 = 128 M-blocks x 2 N-halves. block: 512 thr = 8 waves = 4 mg x 2 kg.
// W staged in 4-pair (256-k) groups, double-buffered; ONE barrier per group.
// h read directly from global (L2-resident tile); x from LDS.
template <int LAYER>
__global__ __launch_bounds__(512, 2) void cin_gemm4(
    const u16* __restrict__ Xbd,    // [32768][40] bf16
    const u16* __restrict__ Hglb,   // global h source (L0: Xbd, else prev layer h)
    const u16* __restrict__ Wp,     // [224][KP] bf16
    const float* __restrict__ bias, // [200] f32
    u16* __restrict__ Hout,         // [32768][208] bf16 (LAYER<2)
    float* __restrict__ out)        // [2048][600] f32
{
    constexpr int KP     = (LAYER == 0) ? 1792 : 8192;
    constexpr int NGROUP = KP / 256;
    constexpr u32 MAGIC  = (LAYER == 0) ? 3277u : 10083u;
    constexpr int SHIFT  = (LAYER == 0) ? 17 : 21;
    constexpr int GS     = (LAYER == 0) ? 40 : 208;    // k = f*GS + g
    constexpr int HROW   = (LAYER == 0) ? 40 : 208;    // global h row stride
    constexpr int WOFF   = 20480;                      // X region = 256*40*2
    constexpr int WBUF   = 57344;                      // 8 chunks x [112][32] u16

    __shared__ __align__(16) char smem[WOFF + 2 * WBUF];   // 135,168 B
    u16* Xl = (u16*)smem;

    const int bid  = blockIdx.x;
    const int mblk = bid >> 1, nblk = bid & 1;
    const int m0    = mblk * 256;
    const int ncol0 = nblk * 112;
    const int NT    = nblk ? 6 : 7;
    const int tid  = threadIdx.x;
    const int lane = tid & 63, wid = tid >> 6;
    const int mg = wid & 3, kg = wid >> 2;
    const int rowl = lane & 15, grp = lane >> 4;

    // ---- stage X (once) ----
    {
        const char* xsrc = (const char*)(Xbd + (size_t)m0 * 40);
        for (int i = wid; i < 20; i += 8)
            GLL(xsrc + i * 1024 + lane * 16, smem + i * 1024);
    }
    // ---- W staging: wave wid stages chunk wid (k-offset wid*32) of each group ----
    const size_t wlsrc = (size_t)(ncol0 + (lane >> 2)) * KP + wid * 32 + (lane & 3) * 8;
    {
        char* wb = smem + WOFF + wid * 7168;
        #pragma unroll
        for (int j = 0; j < 7; ++j)
            GLL((const char*)(Wp + wlsrc + (size_t)j * 16 * KP), wb + j * 1024);
    }

    int xro[4];
    size_t hrg[4];
    #pragma unroll
    for (int s = 0; s < 4; ++s) {
        int r = mg * 64 + s * 16 + rowl;
        xro[s] = r * 40;
        hrg[s] = (size_t)(m0 + r) * HROW;
    }

    f32x4 acc[4][7];
    #pragma unroll
    for (int s = 0; s < 4; ++s)
        #pragma unroll
        for (int t = 0; t < 7; ++t) {
            f32x4 z = {0.f, 0.f, 0.f, 0.f};
            acc[s][t] = z;
        }

    for (int g = 0; g < NGROUP; ++g) {
        __syncthreads();   // drains this wave's W/X loads; syncs buffer reuse
        // issue W loads for group g+1 into the other buffer (4-pair slack)
        if (g + 1 < NGROUP) {
            char* wb = smem + WOFF + ((g + 1) & 1) * WBUF + wid * 7168;
            const u16* gsrc = Wp + wlsrc + (size_t)(g + 1) * 256;
            #pragma unroll
            for (int j = 0; j < 7; ++j)
                GLL((const char*)(gsrc + (size_t)j * 16 * KP), wb + j * 1024);
        }
        const u16* wbase = (const u16*)(smem + WOFF + (g & 1) * WBUF);
        #pragma unroll
        for (int p = 0; p < 4; ++p) {
            // ---- build A fragments for my chunk ----
            int k0 = g * 256 + p * 64 + kg * 32 + grp * 8;
            u32 f = ((u32)k0 * MAGIC) >> SHIFT;
            f = (f > 39u) ? 39u : f;
            int g0 = k0 - (int)f * GS;
            bf16x8 afrag[4];
            #pragma unroll
            for (int s = 0; s < 4; ++s) {
                u16 xs = Xl[xro[s] + (int)f];
                bf16x8 hv = *(const bf16x8*)(Hglb + hrg[s] + g0);
                float xf = __uint_as_float(((u32)xs) << 16);
                union { bf16x8 v; u32 w[4]; } hu, au;
                hu.v = hv;
                #pragma unroll
                for (int j = 0; j < 4; ++j) {
                    float lo = __uint_as_float(hu.w[j] << 16);
                    float hi = __uint_as_float(hu.w[j] & 0xffff0000u);
                    float pl = xf * lo;
                    float ph = xf * hi;
                    u32 pk;
                    asm("v_cvt_pk_bf16_f32 %0, %1, %2" : "=v"(pk) : "v"(pl), "v"(ph));
                    au.w[j] = pk;
                }
                afrag[s] = au.v;
            }
            // ---- B fragments + MFMA ----
            const u16* wbR = wbase + (p * 2 + kg) * 3584 + rowl * 32 + grp * 8;
            #pragma unroll
            for (int t = 0; t < 7; ++t) {
                if (t < NT) {
                    bf16x8 bfrag = *(const bf16x8*)&wbR[t * 512];
                    #pragma unroll
                    for (int s = 0; s < 4; ++s)
                        acc[s][t] = __builtin_amdgcn_mfma_f32_16x16x32_bf16(afrag[s], bfrag, acc[s][t], 0, 0, 0);
                }
            }
        }
    }

    // ---- merge kg pair partials via LDS (reuses smem; X/W dead) ----
    __syncthreads();
    float* red = (float*)smem;
    const int rbase = mg * 7168 + lane * 4;
    if (kg == 1) {
        #pragma unroll
        for (int s = 0; s < 4; ++s)
            #pragma unroll
            for (int t = 0; t < 7; ++t)
                if (t < NT)
                    *(f32x4*)&red[rbase + (s * 7 + t) * 256] = acc[s][t];
    }
    __syncthreads();

    if (kg == 0) {
        float bias_t[7];
        #pragma unroll
        for (int t = 0; t < 7; ++t) {
            int oc = ncol0 + t * 16 + rowl;
            bias_t[t] = (t < NT && oc < 200) ? bias[oc] : 0.0f;
        }
        #pragma unroll
        for (int s = 0; s < 4; ++s) {
            int mrow0 = m0 + mg * 64 + s * 16;   // 16 rows = one batch index
            int bidx = mrow0 >> 4;
            #pragma unroll
            for (int t = 0; t < 7; ++t) {
                if (t < NT) {
                    int oc = ncol0 + t * 16 + rowl;
                    f32x4 o = *(const f32x4*)&red[rbase + (s * 7 + t) * 256];
                    f32x4 v = acc[s][t];
                    float h0 = fmaxf(v[0] + o[0] + bias_t[t], 0.0f);
                    float h1 = fmaxf(v[1] + o[1] + bias_t[t], 0.0f);
                    float h2 = fmaxf(v[2] + o[2] + bias_t[t], 0.0f);
                    float h3 = fmaxf(v[3] + o[3] + bias_t[t], 0.0f);
                    if constexpr (LAYER < 2) {
                        size_t rb = (size_t)(mrow0 + grp * 4) * 208 + oc;
                        Hout[rb]           = f2bf_rne(h0);
                        Hout[rb + 208]     = f2bf_rne(h1);
                        Hout[rb + 2*208]   = f2bf_rne(h2);
                        Hout[rb + 3*208]   = f2bf_rne(h3);
                    }
                    float ssum = (h0 + h1) + (h2 + h3);
                    ssum += __shfl_xor(ssum, 16);
                    ssum += __shfl_xor(ssum, 32);
                    if (grp == 0 && oc < 200)
                        out[(size_t)bidx * 600 + LAYER * 200 + oc] = ssum;
                }
            }
        }
    }
}

// ---------------- launch ----------------
extern "C" void kernel_launch(void* const* d_in, const int* in_sizes, int n_in,
                              void* d_out, int out_size, void* d_ws, size_t ws_size,
                              hipStream_t stream) {
    const float* x  = (const float*)d_in[0];
    const float* W0 = (const float*)d_in[1];
    const float* b0 = (const float*)d_in[2];
    const float* W1 = (const float*)d_in[3];
    const float* b1 = (const float*)d_in[4];
    const float* W2 = (const float*)d_in[5];
    const float* b2 = (const float*)d_in[6];
    float* out = (float*)d_out;

    char* ws = (char*)d_ws;
    // workspace layout (16B aligned, tail slack after xbd/h1/h2 for benign overreads)
    u16* xbd = (u16*)(ws);                     // 32768*40*2  = 2,621,440 (+1024 slack)
    u16* wp0 = (u16*)(ws + 2622464);           // 224*1792*2  =   802,816
    u16* wp1 = (u16*)(ws + 3425280);           // 224*8192*2  = 3,670,016
    u16* wp2 = (u16*)(ws + 7095296);           // 3,670,016
    u16* h1  = (u16*)(ws + 10765312);          // 32768*208*2 = 13,631,488 (+1024 slack)
    u16* h2  = (u16*)(ws + 24397824);          // 13,631,488 (+1024 slack)

    pack_x_kernel<<<5120, 256, 0, stream>>>(x, xbd);
    pack_w0_kernel<<<1568, 256, 0, stream>>>(W0, wp0);
    pack_w12_kernel<<<7168, 256, 0, stream>>>(W1, wp1);
    pack_w12_kernel<<<7168, 256, 0, stream>>>(W2, wp2);

    cin_gemm4<0><<<256, 512, 0, stream>>>(xbd, xbd, wp0, b0, h1, out);
    cin_gemm4<1><<<256, 512, 0, stream>>>(xbd, h1, wp1, b1, h2, out);
    cin_gemm4<2><<<256, 512, 0, stream>>>(xbd, h2, wp2, b2, (u16*)nullptr, out);
}